// Round 3
// baseline (80.547 us; speedup 1.0000x reference)
//
#include <hip/hip_runtime.h>

#define DD 2048
#define BB 16

// ---------------------------------------------------------------------------
// gates v3: one wave = one output column j, FULL K, both gates.
// Block = 4 waves = 4 consecutive columns -> xt loads shared via L1/L2.
// Butterfly reduce (all lanes end with totals), lanes 0..15 finalize b=lane.
// No LDS, no __syncthreads.
// ---------------------------------------------------------------------------
__global__ __launch_bounds__(256) void gates_kernel(
    const float* __restrict__ xt, const float* __restrict__ h,
    const float* __restrict__ Wa, const float* __restrict__ Wx,
    const float* __restrict__ ba, const float* __restrict__ bx,
    const float* __restrict__ Lam,
    float* __restrict__ u_ws, float* __restrict__ dv_ws)
{
    const int t    = threadIdx.x;
    const int wave = t >> 6;
    const int lane = t & 63;
    const int j    = blockIdx.x * 4 + wave;

    const float4* x4  = (const float4*)xt;
    const float4* Wa4 = (const float4*)Wa + (size_t)j * (DD / 4);
    const float4* Wx4 = (const float4*)Wx + (size_t)j * (DD / 4);

    float accA[BB], accX[BB];
#pragma unroll
    for (int b = 0; b < BB; ++b) { accA[b] = 0.f; accX[b] = 0.f; }

    // full K = 512 float4 -> 8 iterations of 64 lanes
#pragma unroll
    for (int it = 0; it < 8; ++it) {
        const int k4 = it * 64 + lane;
        const float4 wa = Wa4[k4];
        const float4 wx = Wx4[k4];
#pragma unroll
        for (int b = 0; b < BB; ++b) {
            const float4 x = x4[b * (DD / 4) + k4];
            accA[b] = fmaf(wa.x, x.x, accA[b]);
            accA[b] = fmaf(wa.y, x.y, accA[b]);
            accA[b] = fmaf(wa.z, x.z, accA[b]);
            accA[b] = fmaf(wa.w, x.w, accA[b]);
            accX[b] = fmaf(wx.x, x.x, accX[b]);
            accX[b] = fmaf(wx.y, x.y, accX[b]);
            accX[b] = fmaf(wx.z, x.z, accX[b]);
            accX[b] = fmaf(wx.w, x.w, accX[b]);
        }
    }

    // 6-step xor butterfly: afterwards EVERY lane holds the full-K total.
#pragma unroll
    for (int b = 0; b < BB; ++b) {
        float a = accA[b], x = accX[b];
#pragma unroll
        for (int m = 1; m < 64; m <<= 1) {
            a += __shfl_xor(a, m, 64);
            x += __shfl_xor(x, m, 64);
        }
        accA[b] = a; accX[b] = x;
    }

    if (lane < BB) {
        // static-unrolled select of acc[lane] (no dynamic register indexing)
        float rA = accA[0], rX = accX[0];
#pragma unroll
        for (int b = 1; b < BB; ++b) {
            if (lane == b) { rA = accA[b]; rX = accX[b]; }
        }
        rA += ba[j];
        rX += bx[j];
        const float rt  = 1.f / (1.f + expf(-rA));
        const float itg = 1.f / (1.f + expf(-rX));
        const float log_a = -log1pf(expf(-Lam[j]));   // -softplus(-Lam)
        const float a = expf(log_a * rt * 0.125f);    // / C, C = 8
        const float u = sqrtf(fmaxf(0.f, 1.f - a * a)) * (itg * xt[lane * DD + j]);
        const float dv = fmaf(a, h[lane * DD + j], u);
        u_ws[lane * DD + j]  = u;
        dv_ws[lane * DD + j] = dv;
    }
}

// ---------------------------------------------------------------------------
// fill (unchanged from R2): out[b,i,:] = u[b,:], diag patched with dv.
// ---------------------------------------------------------------------------
__global__ __launch_bounds__(256) void fill_kernel(
    const float4* __restrict__ u4, const float* __restrict__ dv,
    float4* __restrict__ out)
{
    const int blk = blockIdx.x;       // 0..2047
    const int b   = blk >> 7;         // 0..15
    const int ig  = blk & 127;        // 0..127
    const int i0  = ig << 4;          // 16 rows starting here
    const int t   = threadIdx.x;

    const float4 v0 = u4[(b << 9) + t];         // j4 = t
    const float4 v1 = u4[(b << 9) + 256 + t];   // j4 = 256 + t

    float4* orow = out + ((size_t)b << 20) + ((size_t)i0 << 9);
#pragma unroll
    for (int r = 0; r < 16; ++r) {
        const int i   = i0 + r;
        const int dj4 = i >> 2;
        float4 w0 = v0, w1 = v1;
        if (dj4 == t) {
            ((float*)&w0)[i & 3] = dv[(b << 11) + i];
        } else if (dj4 == 256 + t) {
            ((float*)&w1)[i & 3] = dv[(b << 11) + i];
        }
        orow[t]       = w0;
        orow[256 + t] = w1;
        orow += DD / 4;
    }
}

extern "C" void kernel_launch(void* const* d_in, const int* in_sizes, int n_in,
                              void* d_out, int out_size, void* d_ws, size_t ws_size,
                              hipStream_t stream) {
    const float* xt  = (const float*)d_in[0];
    const float* h   = (const float*)d_in[1];
    const float* Wa  = (const float*)d_in[2];
    const float* Wx  = (const float*)d_in[3];
    const float* ba  = (const float*)d_in[4];
    const float* bx  = (const float*)d_in[5];
    const float* Lam = (const float*)d_in[6];

    float* u_ws  = (float*)d_ws;             // [B, D]
    float* dv_ws = u_ws + BB * DD;           // [B, D]

    gates_kernel<<<DD / 4, 256, 0, stream>>>(xt, h, Wa, Wx, ba, bx, Lam, u_ws, dv_ws);
    fill_kernel<<<BB * (DD / 16), 256, 0, stream>>>((const float4*)u_ws, dv_ws, (float4*)d_out);
}

// Round 5
// 70.287 us; speedup vs baseline: 1.1460x; 1.1460x over previous
//
#include <hip/hip_runtime.h>

#define DD 2048
#define BB 16

typedef float f32x4 __attribute__((ext_vector_type(4)));

// ---------------------------------------------------------------------------
// gates v4: v2 topology (block = 2 cols x 2 K-halves, 16 waves/CU) +
// select-exchange butterfly: 34 shuffles/wave instead of 192.
// After reduction lane L holds the half-K totals for b = L & 15.
// ---------------------------------------------------------------------------
__global__ __launch_bounds__(256) void gates_kernel(
    const float* __restrict__ xt, const float* __restrict__ h,
    const float* __restrict__ Wa, const float* __restrict__ Wx,
    const float* __restrict__ ba, const float* __restrict__ bx,
    const float* __restrict__ Lam,
    float* __restrict__ u_ws, float* __restrict__ dv_ws)
{
    const int j0   = blockIdx.x * 2;
    const int t    = threadIdx.x;
    const int wave = t >> 6;
    const int lane = t & 63;
    const int jj   = wave >> 1;       // which of the 2 columns
    const int half = wave & 1;        // K-half

    const int j = j0 + jj;
    const float4* x4  = (const float4*)xt;
    const float4* Wa4 = (const float4*)Wa + (size_t)j * (DD / 4);
    const float4* Wx4 = (const float4*)Wx + (size_t)j * (DD / 4);

    float accA[BB], accX[BB];
#pragma unroll
    for (int b = 0; b < BB; ++b) { accA[b] = 0.f; accX[b] = 0.f; }

    // K-half = 256 float4 -> 4 iterations of 64 lanes
#pragma unroll
    for (int it = 0; it < 4; ++it) {
        const int k4 = half * 256 + it * 64 + lane;
        const float4 wa = Wa4[k4];
        const float4 wx = Wx4[k4];
#pragma unroll
        for (int b = 0; b < BB; ++b) {
            const float4 x = x4[b * (DD / 4) + k4];
            accA[b] = fmaf(wa.x, x.x, accA[b]);
            accA[b] = fmaf(wa.y, x.y, accA[b]);
            accA[b] = fmaf(wa.z, x.z, accA[b]);
            accA[b] = fmaf(wa.w, x.w, accA[b]);
            accX[b] = fmaf(wx.x, x.x, accX[b]);
            accX[b] = fmaf(wx.y, x.y, accX[b]);
            accX[b] = fmaf(wx.z, x.z, accX[b]);
            accX[b] = fmaf(wx.w, x.w, accX[b]);
        }
    }

    // select-exchange butterfly: steps s=0..3 consume b-bit s against lane-bit s.
    // Invariant: before step s, acc[i] is the partial for b = (i<<s)|(lane&((1<<s)-1)).
#pragma unroll
    for (int s = 0; s < 4; ++s) {
        const int bit = (lane >> s) & 1;
#pragma unroll
        for (int i = 0; i < (BB >> 1); ++i) {
            if (i < (BB >> (s + 1))) {
                const float sendA = bit ? accA[2 * i] : accA[2 * i + 1];
                const float sendX = bit ? accX[2 * i] : accX[2 * i + 1];
                const float recvA = __shfl_xor(sendA, 1 << s, 64);
                const float recvX = __shfl_xor(sendX, 1 << s, 64);
                const float keepA = bit ? accA[2 * i + 1] : accA[2 * i];
                const float keepX = bit ? accX[2 * i + 1] : accX[2 * i];
                accA[i] = keepA + recvA;
                accX[i] = keepX + recvX;
            }
        }
    }
    // cross-group steps: sum over lane bits 4,5
    float rA = accA[0] + __shfl_xor(accA[0], 16, 64);
    rA += __shfl_xor(rA, 32, 64);
    float rX = accX[0] + __shfl_xor(accX[0], 16, 64);
    rX += __shfl_xor(rX, 32, 64);
    // lane L now holds the half-K totals for b = L & 15

    __shared__ float red[2][2][2][BB];   // [jj][half][gate][b]
    if (lane < BB) {
        red[jj][half][0][lane] = rA;
        red[jj][half][1][lane] = rX;
    }
    __syncthreads();

    if (t < 32) {
        const int tj = t >> 4;
        const int b  = t & 15;
        const int jc = j0 + tj;
        const float sA = red[tj][0][0][b] + red[tj][1][0][b] + ba[jc];
        const float sX = red[tj][0][1][b] + red[tj][1][1][b] + bx[jc];
        const float rt  = 1.f / (1.f + expf(-sA));
        const float itg = 1.f / (1.f + expf(-sX));
        const float log_a = -log1pf(expf(-Lam[jc]));    // -softplus(-Lam)
        const float a = expf(log_a * rt * 0.125f);      // / C, C = 8
        const float u = sqrtf(fmaxf(0.f, 1.f - a * a)) * (itg * xt[b * DD + jc]);
        const float dv = fmaf(a, h[b * DD + jc], u);
        u_ws[b * DD + jc]  = u;
        dv_ws[b * DD + jc] = dv;
    }
}

// ---------------------------------------------------------------------------
// fill: out[b,i,:] = u[b,:], diag patched with dv. Nontemporal stores
// (write-once output, skip L2 allocation) via native ext_vector_type.
// ---------------------------------------------------------------------------
__global__ __launch_bounds__(256) void fill_kernel(
    const float4* __restrict__ u4, const float* __restrict__ dv,
    float* __restrict__ out)
{
    const int blk = blockIdx.x;       // 0..2047
    const int b   = blk >> 7;         // 0..15
    const int ig  = blk & 127;        // 0..127
    const int i0  = ig << 4;          // 16 rows starting here
    const int t   = threadIdx.x;

    const float4 v0 = u4[(b << 9) + t];         // j4 = t
    const float4 v1 = u4[(b << 9) + 256 + t];   // j4 = 256 + t

    f32x4* orow = (f32x4*)(out + ((size_t)b << 22) + ((size_t)i0 << 11));
#pragma unroll
    for (int r = 0; r < 16; ++r) {
        const int i   = i0 + r;
        const int dj4 = i >> 2;
        float4 w0 = v0, w1 = v1;
        if (dj4 == t) {
            ((float*)&w0)[i & 3] = dv[(b << 11) + i];
        } else if (dj4 == 256 + t) {
            ((float*)&w1)[i & 3] = dv[(b << 11) + i];
        }
        __builtin_nontemporal_store(*(const f32x4*)&w0, &orow[t]);
        __builtin_nontemporal_store(*(const f32x4*)&w1, &orow[256 + t]);
        orow += DD / 4;
    }
}

extern "C" void kernel_launch(void* const* d_in, const int* in_sizes, int n_in,
                              void* d_out, int out_size, void* d_ws, size_t ws_size,
                              hipStream_t stream) {
    const float* xt  = (const float*)d_in[0];
    const float* h   = (const float*)d_in[1];
    const float* Wa  = (const float*)d_in[2];
    const float* Wx  = (const float*)d_in[3];
    const float* ba  = (const float*)d_in[4];
    const float* bx  = (const float*)d_in[5];
    const float* Lam = (const float*)d_in[6];

    float* u_ws  = (float*)d_ws;             // [B, D]
    float* dv_ws = u_ws + BB * DD;           // [B, D]

    gates_kernel<<<DD / 2, 256, 0, stream>>>(xt, h, Wa, Wx, ba, bx, Lam, u_ws, dv_ws);
    fill_kernel<<<BB * (DD / 16), 256, 0, stream>>>((const float4*)u_ws, dv_ws, (float*)d_out);
}

// Round 6
// 67.792 us; speedup vs baseline: 1.1881x; 1.0368x over previous
//
#include <hip/hip_runtime.h>

#define DD 2048
#define BB 16

// ---------------------------------------------------------------------------
// gates v4 (UNCHANGED from R5 — control for the fill A/B):
// block = 2 cols x 2 K-halves, select-exchange butterfly reduction.
// ---------------------------------------------------------------------------
__global__ __launch_bounds__(256) void gates_kernel(
    const float* __restrict__ xt, const float* __restrict__ h,
    const float* __restrict__ Wa, const float* __restrict__ Wx,
    const float* __restrict__ ba, const float* __restrict__ bx,
    const float* __restrict__ Lam,
    float* __restrict__ u_ws, float* __restrict__ dv_ws)
{
    const int j0   = blockIdx.x * 2;
    const int t    = threadIdx.x;
    const int wave = t >> 6;
    const int lane = t & 63;
    const int jj   = wave >> 1;       // which of the 2 columns
    const int half = wave & 1;        // K-half

    const int j = j0 + jj;
    const float4* x4  = (const float4*)xt;
    const float4* Wa4 = (const float4*)Wa + (size_t)j * (DD / 4);
    const float4* Wx4 = (const float4*)Wx + (size_t)j * (DD / 4);

    float accA[BB], accX[BB];
#pragma unroll
    for (int b = 0; b < BB; ++b) { accA[b] = 0.f; accX[b] = 0.f; }

#pragma unroll
    for (int it = 0; it < 4; ++it) {
        const int k4 = half * 256 + it * 64 + lane;
        const float4 wa = Wa4[k4];
        const float4 wx = Wx4[k4];
#pragma unroll
        for (int b = 0; b < BB; ++b) {
            const float4 x = x4[b * (DD / 4) + k4];
            accA[b] = fmaf(wa.x, x.x, accA[b]);
            accA[b] = fmaf(wa.y, x.y, accA[b]);
            accA[b] = fmaf(wa.z, x.z, accA[b]);
            accA[b] = fmaf(wa.w, x.w, accA[b]);
            accX[b] = fmaf(wx.x, x.x, accX[b]);
            accX[b] = fmaf(wx.y, x.y, accX[b]);
            accX[b] = fmaf(wx.z, x.z, accX[b]);
            accX[b] = fmaf(wx.w, x.w, accX[b]);
        }
    }

    // select-exchange butterfly: 34 shuffles instead of 192.
#pragma unroll
    for (int s = 0; s < 4; ++s) {
        const int bit = (lane >> s) & 1;
#pragma unroll
        for (int i = 0; i < (BB >> 1); ++i) {
            if (i < (BB >> (s + 1))) {
                const float sendA = bit ? accA[2 * i] : accA[2 * i + 1];
                const float sendX = bit ? accX[2 * i] : accX[2 * i + 1];
                const float recvA = __shfl_xor(sendA, 1 << s, 64);
                const float recvX = __shfl_xor(sendX, 1 << s, 64);
                const float keepA = bit ? accA[2 * i + 1] : accA[2 * i];
                const float keepX = bit ? accX[2 * i + 1] : accX[2 * i];
                accA[i] = keepA + recvA;
                accX[i] = keepX + recvX;
            }
        }
    }
    float rA = accA[0] + __shfl_xor(accA[0], 16, 64);
    rA += __shfl_xor(rA, 32, 64);
    float rX = accX[0] + __shfl_xor(accX[0], 16, 64);
    rX += __shfl_xor(rX, 32, 64);
    // lane L holds the half-K totals for b = L & 15

    __shared__ float red[2][2][2][BB];   // [jj][half][gate][b]
    if (lane < BB) {
        red[jj][half][0][lane] = rA;
        red[jj][half][1][lane] = rX;
    }
    __syncthreads();

    if (t < 32) {
        const int tj = t >> 4;
        const int b  = t & 15;
        const int jc = j0 + tj;
        const float sA = red[tj][0][0][b] + red[tj][1][0][b] + ba[jc];
        const float sX = red[tj][0][1][b] + red[tj][1][1][b] + bx[jc];
        const float rt  = 1.f / (1.f + expf(-sA));
        const float itg = 1.f / (1.f + expf(-sX));
        const float log_a = -log1pf(expf(-Lam[jc]));    // -softplus(-Lam)
        const float a = expf(log_a * rt * 0.125f);      // / C, C = 8
        const float u = sqrtf(fmaxf(0.f, 1.f - a * a)) * (itg * xt[b * DD + jc]);
        const float dv = fmaf(a, h[b * DD + jc], u);
        u_ws[b * DD + jc]  = u;
        dv_ws[b * DD + jc] = dv;
    }
}

// ---------------------------------------------------------------------------
// fill v3: plain (cached) stores — NT removed; 4096 blocks x 8 rows for
// finer interleave / shorter tail. Everything else as R5.
// ---------------------------------------------------------------------------
__global__ __launch_bounds__(256) void fill_kernel(
    const float4* __restrict__ u4, const float* __restrict__ dv,
    float4* __restrict__ out)
{
    const int blk = blockIdx.x;       // 0..4095
    const int b   = blk >> 8;         // 0..15
    const int ig  = blk & 255;        // 0..255
    const int i0  = ig << 3;          // 8 rows starting here
    const int t   = threadIdx.x;

    const float4 v0 = u4[(b << 9) + t];         // j4 = t
    const float4 v1 = u4[(b << 9) + 256 + t];   // j4 = 256 + t

    float4* orow = out + ((size_t)b << 20) + ((size_t)i0 << 9);
#pragma unroll
    for (int r = 0; r < 8; ++r) {
        const int i   = i0 + r;
        const int dj4 = i >> 2;
        float4 w0 = v0, w1 = v1;
        if (dj4 == t) {
            ((float*)&w0)[i & 3] = dv[(b << 11) + i];
        } else if (dj4 == 256 + t) {
            ((float*)&w1)[i & 3] = dv[(b << 11) + i];
        }
        orow[t]       = w0;
        orow[256 + t] = w1;
        orow += DD / 4;
    }
}

extern "C" void kernel_launch(void* const* d_in, const int* in_sizes, int n_in,
                              void* d_out, int out_size, void* d_ws, size_t ws_size,
                              hipStream_t stream) {
    const float* xt  = (const float*)d_in[0];
    const float* h   = (const float*)d_in[1];
    const float* Wa  = (const float*)d_in[2];
    const float* Wx  = (const float*)d_in[3];
    const float* ba  = (const float*)d_in[4];
    const float* bx  = (const float*)d_in[5];
    const float* Lam = (const float*)d_in[6];

    float* u_ws  = (float*)d_ws;             // [B, D]
    float* dv_ws = u_ws + BB * DD;           // [B, D]

    gates_kernel<<<DD / 2, 256, 0, stream>>>(xt, h, Wa, Wx, ba, bx, Lam, u_ws, dv_ws);
    fill_kernel<<<BB * (DD / 8), 256, 0, stream>>>((const float4*)u_ws, dv_ws, (float4*)d_out);
}

// Round 7
// 61.656 us; speedup vs baseline: 1.3064x; 1.0995x over previous
//
#include <hip/hip_runtime.h>

#define DD 2048
#define BB 16

typedef float f32x4 __attribute__((ext_vector_type(4)));
typedef short bf16x8 __attribute__((ext_vector_type(8)));

static __device__ inline short f2bf(float f) {
    unsigned u = __builtin_bit_cast(unsigned, f);
    return (short)((u + 0x7fffu + ((u >> 16) & 1u)) >> 16);   // RNE
}

static __device__ inline bf16x8 cvt8(f32x4 a, f32x4 b) {
    bf16x8 r;
#pragma unroll
    for (int e = 0; e < 4; ++e) {
        r[e]     = f2bf(a[e]);
        r[4 + e] = f2bf(b[e]);
    }
    return r;
}

// ---------------------------------------------------------------------------
// gemm: raw[gate][b][j] = sum_k W_gate[j,k] * xt[b,k]  via bf16 MFMA.
// Block = (j-tile of 16, gate); 8 waves = 8 K-ranges of 256 (8 MFMAs each).
// A-frag: lane l holds W[j0+(l&15)][kc*8 .. +7], kc = l>>4 (k-consistent with B).
// B-frag: lane l holds xt[l&15][kc*8 .. +7].
// C/D (m89-verified): col = l&15 (b), row = (l>>4)*4 + reg (j within tile).
// ---------------------------------------------------------------------------
__global__ __launch_bounds__(512) void gemm_kernel(
    const float* __restrict__ xt,
    const float* __restrict__ Wa, const float* __restrict__ Wx,
    float* __restrict__ rawA, float* __restrict__ rawX)
{
    const int gate = blockIdx.x & 1;
    const int jt   = blockIdx.x >> 1;
    const int wv   = threadIdx.x >> 6;    // 0..7 : K-range
    const int lane = threadIdx.x & 63;
    const int mn   = lane & 15;
    const int kc   = lane >> 4;           // 0..3

    const float* W = gate ? Wx : Wa;
    const float* wrow = W  + (size_t)(jt * 16 + mn) * DD;
    const float* xrow = xt + (size_t)mn * DD;
    const int kbase = wv * 256 + kc * 8;

    f32x4 acc = {0.f, 0.f, 0.f, 0.f};
#pragma unroll
    for (int s = 0; s < 8; ++s) {
        const int k = kbase + s * 32;
        const f32x4 wa0 = *(const f32x4*)(wrow + k);
        const f32x4 wa1 = *(const f32x4*)(wrow + k + 4);
        const f32x4 xb0 = *(const f32x4*)(xrow + k);
        const f32x4 xb1 = *(const f32x4*)(xrow + k + 4);
        const bf16x8 af = cvt8(wa0, wa1);
        const bf16x8 bf_ = cvt8(xb0, xb1);
        acc = __builtin_amdgcn_mfma_f32_16x16x32_bf16(af, bf_, acc, 0, 0, 0);
    }

    __shared__ float part[8][256];
#pragma unroll
    for (int r = 0; r < 4; ++r) part[wv][lane * 4 + r] = acc[r];
    __syncthreads();

    if (threadIdx.x < 256) {
        const int t = threadIdx.x;
        float s = 0.f;
#pragma unroll
        for (int w = 0; w < 8; ++w) s += part[w][t];
        const int l   = t >> 2;
        const int r   = t & 3;
        const int row = ((l >> 4) << 2) + r;   // j within tile
        const int col = l & 15;                // b
        float* dst = gate ? rawX : rawA;
        dst[col * DD + jt * 16 + row] = s;
    }
}

// ---------------------------------------------------------------------------
// finalize: in-place RMW of raw -> u (in rawA slot) and dv (in rawX slot).
// One thread per (b, j) pair; 32768 total.
// ---------------------------------------------------------------------------
__global__ __launch_bounds__(256) void finalize_kernel(
    const float* __restrict__ xt, const float* __restrict__ h,
    const float* __restrict__ ba, const float* __restrict__ bx,
    const float* __restrict__ Lam,
    float* __restrict__ rawA_u, float* __restrict__ rawX_dv)
{
    const int g = blockIdx.x * 256 + threadIdx.x;   // 0..32767
    const int b = g >> 11;
    const int j = g & (DD - 1);

    const float sA = rawA_u[g] + ba[j];
    const float sX = rawX_dv[g] + bx[j];
    const float rt  = 1.f / (1.f + expf(-sA));
    const float itg = 1.f / (1.f + expf(-sX));
    const float log_a = -log1pf(expf(-Lam[j]));    // -softplus(-Lam)
    const float a = expf(log_a * rt * 0.125f);     // / C, C = 8
    const float u = sqrtf(fmaxf(0.f, 1.f - a * a)) * (itg * xt[b * DD + j]);
    const float dv = fmaf(a, h[b * DD + j], u);
    rawA_u[g]  = u;
    rawX_dv[g] = dv;
}

// ---------------------------------------------------------------------------
// fill (unchanged from R6): out[b,i,:] = u[b,:], diag patched with dv.
// ---------------------------------------------------------------------------
__global__ __launch_bounds__(256) void fill_kernel(
    const float4* __restrict__ u4, const float* __restrict__ dv,
    float4* __restrict__ out)
{
    const int blk = blockIdx.x;       // 0..4095
    const int b   = blk >> 8;         // 0..15
    const int ig  = blk & 255;        // 0..255
    const int i0  = ig << 3;          // 8 rows starting here
    const int t   = threadIdx.x;

    const float4 v0 = u4[(b << 9) + t];         // j4 = t
    const float4 v1 = u4[(b << 9) + 256 + t];   // j4 = 256 + t

    float4* orow = out + ((size_t)b << 20) + ((size_t)i0 << 9);
#pragma unroll
    for (int r = 0; r < 8; ++r) {
        const int i   = i0 + r;
        const int dj4 = i >> 2;
        float4 w0 = v0, w1 = v1;
        if (dj4 == t) {
            ((float*)&w0)[i & 3] = dv[(b << 11) + i];
        } else if (dj4 == 256 + t) {
            ((float*)&w1)[i & 3] = dv[(b << 11) + i];
        }
        orow[t]       = w0;
        orow[256 + t] = w1;
        orow += DD / 4;
    }
}

extern "C" void kernel_launch(void* const* d_in, const int* in_sizes, int n_in,
                              void* d_out, int out_size, void* d_ws, size_t ws_size,
                              hipStream_t stream) {
    const float* xt  = (const float*)d_in[0];
    const float* h   = (const float*)d_in[1];
    const float* Wa  = (const float*)d_in[2];
    const float* Wx  = (const float*)d_in[3];
    const float* ba  = (const float*)d_in[4];
    const float* bx  = (const float*)d_in[5];
    const float* Lam = (const float*)d_in[6];

    float* ws0 = (float*)d_ws;           // rawA -> u   [B, D]
    float* ws1 = ws0 + BB * DD;          // rawX -> dv  [B, D]

    gemm_kernel<<<256, 512, 0, stream>>>(xt, Wa, Wx, ws0, ws1);
    finalize_kernel<<<BB * DD / 256, 256, 0, stream>>>(xt, h, ba, bx, Lam, ws0, ws1);
    fill_kernel<<<BB * (DD / 8), 256, 0, stream>>>((const float4*)ws0, ws1, (float4*)d_out);
}